// Round 7
// baseline (342.709 us; speedup 1.0000x reference)
//
#include <hip/hip_runtime.h>

#define NUMH 16
#define HD   64
#define SEQ  2048
#define NB   2
#define DIM  1024
#define MROWS (NB * SEQ)

typedef __attribute__((ext_vector_type(8))) short short8;
typedef __attribute__((ext_vector_type(4))) float f32x4;
typedef unsigned short u16;
typedef unsigned int u32;

__device__ inline u16 bf16_rn(float f) {
    unsigned u = __float_as_uint(f);
    return (u16)((u + 0x7FFFu + ((u >> 16) & 1u)) >> 16);
}
__device__ inline float bf16f(u16 h) {
    return __uint_as_float(((unsigned)h) << 16);
}

// Async global->LDS DMA, 16B per lane. LDS dest = wave-uniform base + lane*16.
#define GLD16(gp, lp)                                                        \
    __builtin_amdgcn_global_load_lds(                                        \
        (const __attribute__((address_space(1))) void*)(gp),                 \
        (__attribute__((address_space(3))) void*)(lp), 16, 0, 0)

// ---------------------------------------------------------------------------
// fp32 -> bf16 hi/lo split, elementwise ([M][K] kept)
// ---------------------------------------------------------------------------
__global__ void convert_split(const float* __restrict__ in,
                              u16* __restrict__ hi, u16* __restrict__ lo, int n4)
{
    for (int i = blockIdx.x * blockDim.x + threadIdx.x; i < n4;
         i += gridDim.x * blockDim.x) {
        const float4 v = ((const float4*)in)[i];
        ushort4 h, l;
        h.x = bf16_rn(v.x); l.x = bf16_rn(v.x - bf16f(h.x));
        h.y = bf16_rn(v.y); l.y = bf16_rn(v.y - bf16f(h.y));
        h.z = bf16_rn(v.z); l.z = bf16_rn(v.z - bf16f(h.z));
        h.w = bf16_rn(v.w); l.w = bf16_rn(v.w - bf16f(h.w));
        ((ushort4*)hi)[i] = h;
        ((ushort4*)lo)[i] = l;
    }
}

// ---------------------------------------------------------------------------
// W [K][N] fp32 -> Wt_hi/Wt_lo [N][K] bf16 (transpose + split), * scale
// ---------------------------------------------------------------------------
__global__ __launch_bounds__(256)
void transpose_split(const float* __restrict__ W,
                     u16* __restrict__ th, u16* __restrict__ tl, float scale)
{
    __shared__ float Ls[32][33];
    const int tx = threadIdx.x & 31, ty = threadIdx.x >> 5;
    const int k0 = blockIdx.x * 32, n0 = blockIdx.y * 32;
#pragma unroll
    for (int i = 0; i < 4; ++i)
        Ls[ty + 8 * i][tx] = W[(size_t)(k0 + ty + 8 * i) * DIM + n0 + tx];
    __syncthreads();
#pragma unroll
    for (int i = 0; i < 4; ++i) {
        const float f = Ls[tx][ty + 8 * i] * scale;
        const u16 h = bf16_rn(f);
        const u16 l = bf16_rn(f - bf16f(h));
        th[(size_t)(n0 + ty + 8 * i) * DIM + k0 + tx] = h;
        tl[(size_t)(n0 + ty + 8 * i) * DIM + k0 + tx] = l;
    }
}

// ---------------------------------------------------------------------------
// bf16-split MFMA GEMM, staging via global_load_lds (m97 2-barrier structure).
// EPI 0: fp32 [M][DIM]; EPI 1: bf16 h/l scatter [B,H,S,Hd]; EPI 2: bf16 h
// scatter [B,H,Hd,S] (V transposed, packed ushort4).
// ---------------------------------------------------------------------------
template<int EPI>
__global__ __launch_bounds__(256, 2)
void gemm_split(const u16* __restrict__ Ah, const u16* __restrict__ Al,
                const u16* __restrict__ Bh, const u16* __restrict__ Bl,
                const float* __restrict__ bias, float bscale,
                float* __restrict__ outF, u16* __restrict__ outH,
                u16* __restrict__ outL)
{
    __shared__ u16 AsH[128][32];
    __shared__ u16 AsL[128][32];
    __shared__ u16 BsH[64][32];
    __shared__ u16 BsL[64][32];

    const int tid  = threadIdx.x;
    const int m0   = blockIdx.x * 128;
    const int n0   = blockIdx.y * 64;
    const int wid  = tid >> 6;
    const int lane = tid & 63;
    const int wr   = wid >> 1;
    const int wc   = wid & 1;
    const int fr   = lane & 15;
    const int fg   = lane >> 4;
    const int K    = DIM;

    f32x4 acc[4][2];
#pragma unroll
    for (int i = 0; i < 4; ++i)
#pragma unroll
        for (int j = 0; j < 2; ++j) { f32x4 z = {0.f, 0.f, 0.f, 0.f}; acc[i][j] = z; }

    // DMA staging geometry: lane l -> LDS byte (wave_base + l*16)
    //   row within 16-row wave chunk = l>>2, col elems = (l&3)*8
    const int gr = (wid << 4) + (lane >> 2);   // tile row this lane fetches
    const int gc = (lane & 3) * 8;             // elem col within K-chunk

    for (int kt = 0; kt < K; kt += 32) {
        __syncthreads();   // prev tile's LDS reads done
        GLD16(&Ah[(size_t)(m0 + gr) * K + kt + gc],      &AsH[(wid << 4)][0]);
        GLD16(&Ah[(size_t)(m0 + 64 + gr) * K + kt + gc], &AsH[64 + (wid << 4)][0]);
        GLD16(&Al[(size_t)(m0 + gr) * K + kt + gc],      &AsL[(wid << 4)][0]);
        GLD16(&Al[(size_t)(m0 + 64 + gr) * K + kt + gc], &AsL[64 + (wid << 4)][0]);
        GLD16(&Bh[(size_t)(n0 + gr) * K + kt + gc],      &BsH[(wid << 4)][0]);
        GLD16(&Bl[(size_t)(n0 + gr) * K + kt + gc],      &BsL[(wid << 4)][0]);
        __syncthreads();   // vmcnt drained by compiler before barrier -> ready

        short8 afh[4], afl[4], bfh[2], bfl[2];
#pragma unroll
        for (int i = 0; i < 4; ++i) {
            afh[i] = *(const short8*)&AsH[wr * 64 + i * 16 + fr][fg * 8];
            afl[i] = *(const short8*)&AsL[wr * 64 + i * 16 + fr][fg * 8];
        }
#pragma unroll
        for (int j = 0; j < 2; ++j) {
            bfh[j] = *(const short8*)&BsH[wc * 32 + j * 16 + fr][fg * 8];
            bfl[j] = *(const short8*)&BsL[wc * 32 + j * 16 + fr][fg * 8];
        }
#pragma unroll
        for (int i = 0; i < 4; ++i)
#pragma unroll
            for (int j = 0; j < 2; ++j) {
                acc[i][j] = __builtin_amdgcn_mfma_f32_16x16x32_bf16(afl[i], bfh[j], acc[i][j], 0, 0, 0);
                acc[i][j] = __builtin_amdgcn_mfma_f32_16x16x32_bf16(afh[i], bfl[j], acc[i][j], 0, 0, 0);
                acc[i][j] = __builtin_amdgcn_mfma_f32_16x16x32_bf16(afh[i], bfh[j], acc[i][j], 0, 0, 0);
            }
    }

#pragma unroll
    for (int i = 0; i < 4; ++i)
#pragma unroll
        for (int j = 0; j < 2; ++j) {
            const int col = n0 + wc * 32 + j * 16 + fr;
            const float bv = bias[col] * bscale;
            if (EPI == 2) {
                const int row = m0 + wr * 64 + i * 16 + fg * 4;
                const int b  = row >> 11;
                const int s  = row & (SEQ - 1);
                const int hh = col >> 6;
                const int hd = col & (HD - 1);
                ushort4 pk;
                pk.x = bf16_rn(acc[i][j][0] + bv);
                pk.y = bf16_rn(acc[i][j][1] + bv);
                pk.z = bf16_rn(acc[i][j][2] + bv);
                pk.w = bf16_rn(acc[i][j][3] + bv);
                *(ushort4*)&outH[((size_t)(b * NUMH + hh) * HD + hd) * SEQ + s] = pk;
            } else {
#pragma unroll
                for (int r = 0; r < 4; ++r) {
                    const int row = m0 + wr * 64 + i * 16 + fg * 4 + r;
                    const float v = acc[i][j][r] + bv;
                    if (EPI == 0) {
                        outF[(size_t)row * DIM + col] = v;
                    } else {
                        const int b  = row >> 11;
                        const int s  = row & (SEQ - 1);
                        const int hh = col >> 6;
                        const int hd = col & (HD - 1);
                        const size_t idx = ((size_t)(b * NUMH + hh) * SEQ + s) * HD + hd;
                        const u16 hv = bf16_rn(v);
                        outH[idx] = hv;
                        outL[idx] = bf16_rn(v - bf16f(hv));
                    }
                }
            }
        }
}

// ---------------------------------------------------------------------------
// MFMA flash attention v3: UN-PAIRED (1024 blocks = 4 blocks/CU), heavy-first
// dispatch, bh-contiguous XCD chunking (K/V L2-resident per XCD). Swapped
// QK^T, XOR-swizzled LDS, reg-prefetch staging, bpermute P-redistribute.
// Q pre-scaled by 0.125 (folded into Wq/bq).
// ---------------------------------------------------------------------------
__global__ __launch_bounds__(256, 4)
void attn_mfma3(const u16* __restrict__ Qh, const u16* __restrict__ Ql,
                const u16* __restrict__ Kh, const u16* __restrict__ Kl,
                const u16* __restrict__ Vt,
                u16* __restrict__ ctxH, u16* __restrict__ ctxL)
{
    __shared__ u16 KsH[64 * 64];
    __shared__ u16 KsL[64 * 64];
    __shared__ u16 Vs [64 * 64];

    const int tid  = threadIdx.x;
    const int w    = tid >> 6;
    const int lane = tid & 63;
    const int lc   = lane & 15;
    const int g    = lane >> 4;

    // bijective: XCD x gets bh in [x*4, x*4+4); within each bh, qt descends
    const int orig = blockIdx.x;
    const int swz  = (orig & 7) * 128 + (orig >> 3);
    const int bh   = swz >> 5;
    const int qt   = 31 - (swz & 31);
    const int NT   = qt + 1;

    const int bb = bh >> 4, hq = bh & 15;
    const size_t kqBase = (size_t)bh * SEQ * HD;
    const size_t vBase  = (size_t)bh * HD * SEQ;

    // Q B-frags: lane holds Q[q = lc][d = s2*32 + g*8 + j]
    short8 qh[2], ql[2];
    {
        const size_t ra = kqBase + (size_t)(qt * 64 + w * 16 + lc) * HD;
        qh[0] = *(const short8*)&Qh[ra + g * 8];  qh[1] = *(const short8*)&Qh[ra + 32 + g * 8];
        ql[0] = *(const short8*)&Ql[ra + g * 8];  ql[1] = *(const short8*)&Ql[ra + 32 + g * 8];
    }

    f32x4 o[4];
#pragma unroll
    for (int f4 = 0; f4 < 4; ++f4) { f32x4 z = {0.f, 0.f, 0.f, 0.f}; o[f4] = z; }
    float mrun = -1e30f, lrun = 0.f;

    // staging: thread -> row tid>>2, 2x16B at col (tid&3)*16; swizzle ^((row&7)<<3)
    const int srow = tid >> 2;
    const int scol = (tid & 3) * 16;
    const int sw   = (srow & 7) << 3;
    const int so1  = srow * 64 + (scol ^ sw);
    const int so2  = srow * 64 + ((scol + 8) ^ sw);
    const int rsw  = (lc & 7) << 3;          // read-side swizzle

    short8 pf[6];
    auto LOADT = [&](int kt) {
        const size_t kg = kqBase + (size_t)(kt * 64 + srow) * HD + scol;
        pf[0] = *(const short8*)&Kh[kg];      pf[1] = *(const short8*)&Kh[kg + 8];
        pf[2] = *(const short8*)&Kl[kg];      pf[3] = *(const short8*)&Kl[kg + 8];
        const size_t vg = vBase + (size_t)srow * SEQ + kt * 64 + scol;
        pf[4] = *(const short8*)&Vt[vg];      pf[5] = *(const short8*)&Vt[vg + 8];
    };
    LOADT(0);

    // bpermute constants for P redistribution
    const int a0 = (((g & 1) * 2 + 0) * 16 + lc) * 4;
    const int a1 = (((g & 1) * 2 + 1) * 16 + lc) * 4;
    const bool hi = ((g >> 1) & 1) != 0;

    for (int kt = 0; kt < NT; ++kt) {
        __syncthreads();                     // prev tile's LDS reads done
        *(short8*)&KsH[so1] = pf[0];  *(short8*)&KsH[so2] = pf[1];
        *(short8*)&KsL[so1] = pf[2];  *(short8*)&KsL[so2] = pf[3];
        *(short8*)&Vs [so1] = pf[4];  *(short8*)&Vs [so2] = pf[5];
        __syncthreads();                     // tile ready
        if (kt + 1 < NT) LOADT(kt + 1);      // prefetch hides under compute

        const int k0 = kt * 64;

        // ---- scores: S^T[k][q] = mfma(K-frag, Q-frag) ----
        f32x4 sf[4];
#pragma unroll
        for (int f4 = 0; f4 < 4; ++f4) {
            f32x4 a = {0.f, 0.f, 0.f, 0.f};
#pragma unroll
            for (int s2 = 0; s2 < 2; ++s2) {
                const int off = (f4 * 16 + lc) * 64 + ((s2 * 32 + g * 8) ^ rsw);
                const short8 kh = *(const short8*)&KsH[off];
                const short8 kl = *(const short8*)&KsL[off];
                a = __builtin_amdgcn_mfma_f32_16x16x32_bf16(kh, ql[s2], a, 0, 0, 0);
                a = __builtin_amdgcn_mfma_f32_16x16x32_bf16(kl, qh[s2], a, 0, 0, 0);
                a = __builtin_amdgcn_mfma_f32_16x16x32_bf16(kh, qh[s2], a, 0, 0, 0);
            }
            sf[f4] = a;
        }

        // ---- mask + row-max + online-softmax (per-lane scalar state) ----
        const bool diag = (kt == qt);
        const int  qg   = qt * 64 + w * 16 + lc;
        float pm = -1e30f;
#pragma unroll
        for (int f4 = 0; f4 < 4; ++f4)
#pragma unroll
            for (int r = 0; r < 4; ++r) {
                float sv = sf[f4][r];
                if (diag && (k0 + f4 * 16 + g * 4 + r > qg)) sv = -1e30f;
                sf[f4][r] = sv;
                pm = fmaxf(pm, sv);
            }
        pm = fmaxf(pm, __shfl_xor(pm, 16));
        pm = fmaxf(pm, __shfl_xor(pm, 32));
        const float mn = fmaxf(mrun, pm);
        const float sc = __expf(mrun - mn);
        mrun = mn; lrun *= sc;
#pragma unroll
        for (int f4 = 0; f4 < 4; ++f4) o[f4] *= sc;

        float ps = 0.f;
        u32 pk[4][2];
#pragma unroll
        for (int f4 = 0; f4 < 4; ++f4)
#pragma unroll
            for (int pr = 0; pr < 2; ++pr) {
                const float p0 = __expf(sf[f4][pr * 2 + 0] - mn);
                const float p1 = __expf(sf[f4][pr * 2 + 1] - mn);
                ps += p0 + p1;
                pk[f4][pr] = (u32)bf16_rn(p0) | ((u32)bf16_rn(p1) << 16);
            }
        ps += __shfl_xor(ps, 16);
        ps += __shfl_xor(ps, 32);
        lrun += ps;

        // ---- in-register P redistribute to PV B-frag layout ----
        u32 pb[2][4];
#pragma unroll
        for (int s2 = 0; s2 < 2; ++s2)
#pragma unroll
            for (int mm = 0; mm < 4; ++mm) {
                const int addr = (mm < 2) ? a0 : a1;
                const u32 t0 = (u32)__builtin_amdgcn_ds_bpermute(addr, (int)pk[s2 * 2 + 0][mm & 1]);
                const u32 t1 = (u32)__builtin_amdgcn_ds_bpermute(addr, (int)pk[s2 * 2 + 1][mm & 1]);
                pb[s2][mm] = hi ? t1 : t0;
            }

        // ---- PV: o^T[d][q] += mfma(V^T-frag, P^T-frag) ----
#pragma unroll
        for (int s2 = 0; s2 < 2; ++s2) {
            union { u32 u[4]; short8 s; } ua;
#pragma unroll
            for (int mm = 0; mm < 4; ++mm) ua.u[mm] = pb[s2][mm];
#pragma unroll
            for (int f4 = 0; f4 < 4; ++f4) {
                const int off = (f4 * 16 + lc) * 64 + ((s2 * 32 + g * 8) ^ rsw);
                const short8 vv = *(const short8*)&Vs[off];
                o[f4] = __builtin_amdgcn_mfma_f32_16x16x32_bf16(vv, ua.s, o[f4], 0, 0, 0);
            }
        }
    }

    // ---- epilogue: o^T[d][q]/l -> ctx bf16 h/l [M][DIM] ----
    const float iv = 1.f / lrun;
    const size_t rowA = (size_t)bb * SEQ + qt * 64 + w * 16 + lc;
#pragma unroll
    for (int f4 = 0; f4 < 4; ++f4) {
        const int colb = hq * HD + f4 * 16 + g * 4;
        ushort4 h4, l4;
#pragma unroll
        for (int r = 0; r < 4; ++r) {
            const float v = o[f4][r] * iv;
            const u16 hv = bf16_rn(v);
            ((u16*)&h4)[r] = hv;
            ((u16*)&l4)[r] = bf16_rn(v - bf16f(hv));
        }
        *(ushort4*)&ctxH[rowA * DIM + colb] = h4;
        *(ushort4*)&ctxL[rowA * DIM + colb] = l4;
    }
}

// ---------------------------------------------------------------------------
extern "C" void kernel_launch(void* const* d_in, const int* in_sizes, int n_in,
                              void* d_out, int out_size, void* d_ws, size_t ws_size,
                              hipStream_t stream)
{
    const float* x  = (const float*)d_in[0];
    const float* Wq = (const float*)d_in[1];
    const float* bq = (const float*)d_in[2];
    const float* Wk = (const float*)d_in[3];
    const float* bk = (const float*)d_in[4];
    const float* Wv = (const float*)d_in[5];
    const float* bv = (const float*)d_in[6];
    const float* Wo = (const float*)d_in[7];
    const float* bo = (const float*)d_in[8];

    char* base = (char*)d_ws;
    const size_t MB = 1024 * 1024;
    u16* Qh_ = (u16*)(base + 0 * MB);
    u16* Ql_ = (u16*)(base + 8 * MB);
    u16* Kh_ = (u16*)(base + 16 * MB);
    u16* Kl_ = (u16*)(base + 24 * MB);
    u16* Vt_ = (u16*)(base + 32 * MB);
    u16* xh  = (u16*)(base + 40 * MB);   // reused as ctxH
    u16* xl  = (u16*)(base + 48 * MB);   // reused as ctxL
    u16* Wth = (u16*)(base + 56 * MB);
    u16* Wtl = (u16*)(base + 58 * MB);

    dim3 blk(256);
    dim3 gg(MROWS / 128, DIM / 64);
    dim3 gt(DIM / 32, DIM / 32);

    hipLaunchKernelGGL(convert_split, dim3(2048), blk, 0, stream,
                       x, xh, xl, MROWS * DIM / 4);

    // Q projection carries the 1/sqrt(Hd)=0.125 scale (exact in bf16 split)
    hipLaunchKernelGGL(transpose_split, gt, blk, 0, stream, Wq, Wth, Wtl, 0.125f);
    hipLaunchKernelGGL((gemm_split<1>), gg, blk, 0, stream,
                       xh, xl, Wth, Wtl, bq, 0.125f, nullptr, Qh_, Ql_);

    hipLaunchKernelGGL(transpose_split, gt, blk, 0, stream, Wk, Wth, Wtl, 1.0f);
    hipLaunchKernelGGL((gemm_split<1>), gg, blk, 0, stream,
                       xh, xl, Wth, Wtl, bk, 1.0f, nullptr, Kh_, Kl_);

    hipLaunchKernelGGL(transpose_split, gt, blk, 0, stream, Wv, Wth, Wtl, 1.0f);
    hipLaunchKernelGGL((gemm_split<2>), gg, blk, 0, stream,
                       xh, xl, Wth, Wtl, bv, 1.0f, nullptr, Vt_, nullptr);

    hipLaunchKernelGGL(attn_mfma3, dim3(NB * NUMH * 32), blk, 0, stream,
                       Qh_, Kh_ ? Ql_ : Ql_, Kh_, Kl_, Vt_, xh, xl);   // ctx -> xh/xl

    hipLaunchKernelGGL(transpose_split, gt, blk, 0, stream, Wo, Wth, Wtl, 1.0f);
    hipLaunchKernelGGL((gemm_split<0>), gg, blk, 0, stream,
                       xh, xl, Wth, Wtl, bo, 1.0f, (float*)d_out, nullptr, nullptr);
}

// Round 9
// 319.727 us; speedup vs baseline: 1.0719x; 1.0719x over previous
//
#include <hip/hip_runtime.h>

#define NUMH 16
#define HD   64
#define SEQ  2048
#define NB   2
#define DIM  1024
#define MROWS (NB * SEQ)

typedef __attribute__((ext_vector_type(8))) short short8;
typedef __attribute__((ext_vector_type(4))) float f32x4;
typedef unsigned short u16;
typedef unsigned int u32;

__device__ inline u16 bf16_rn(float f) {
    unsigned u = __float_as_uint(f);
    return (u16)((u + 0x7FFFu + ((u >> 16) & 1u)) >> 16);
}
__device__ inline float bf16f(u16 h) {
    return __uint_as_float(((unsigned)h) << 16);
}

// Async global->LDS DMA, 16B per lane. LDS dest = wave-uniform base + lane*16.
#define GLD16(gp, lp)                                                        \
    __builtin_amdgcn_global_load_lds(                                        \
        (const __attribute__((address_space(1))) void*)(gp),                 \
        (__attribute__((address_space(3))) void*)(lp), 16, 0, 0)

// ---------------------------------------------------------------------------
// fp32 -> bf16 hi/lo split, elementwise ([M][K] kept)
// ---------------------------------------------------------------------------
__global__ void convert_split(const float* __restrict__ in,
                              u16* __restrict__ hi, u16* __restrict__ lo, int n4)
{
    for (int i = blockIdx.x * blockDim.x + threadIdx.x; i < n4;
         i += gridDim.x * blockDim.x) {
        const float4 v = ((const float4*)in)[i];
        ushort4 h, l;
        h.x = bf16_rn(v.x); l.x = bf16_rn(v.x - bf16f(h.x));
        h.y = bf16_rn(v.y); l.y = bf16_rn(v.y - bf16f(h.y));
        h.z = bf16_rn(v.z); l.z = bf16_rn(v.z - bf16f(h.z));
        h.w = bf16_rn(v.w); l.w = bf16_rn(v.w - bf16f(h.w));
        ((ushort4*)hi)[i] = h;
        ((ushort4*)lo)[i] = l;
    }
}

// ---------------------------------------------------------------------------
// W [K][N] fp32 -> Wt_hi/Wt_lo [N][K] bf16 (transpose + split), * scale
// ---------------------------------------------------------------------------
__global__ __launch_bounds__(256)
void transpose_split(const float* __restrict__ W,
                     u16* __restrict__ th, u16* __restrict__ tl, float scale)
{
    __shared__ float Ls[32][33];
    const int tx = threadIdx.x & 31, ty = threadIdx.x >> 5;
    const int k0 = blockIdx.x * 32, n0 = blockIdx.y * 32;
#pragma unroll
    for (int i = 0; i < 4; ++i)
        Ls[ty + 8 * i][tx] = W[(size_t)(k0 + ty + 8 * i) * DIM + n0 + tx];
    __syncthreads();
#pragma unroll
    for (int i = 0; i < 4; ++i) {
        const float f = Ls[tx][ty + 8 * i] * scale;
        const u16 h = bf16_rn(f);
        const u16 l = bf16_rn(f - bf16f(h));
        th[(size_t)(n0 + ty + 8 * i) * DIM + k0 + tx] = h;
        tl[(size_t)(n0 + ty + 8 * i) * DIM + k0 + tx] = l;
    }
}

// ---------------------------------------------------------------------------
// bf16-split MFMA GEMM, GLD16 staging, m97 2-barrier structure.
// Occupancy fix: launch_bounds(256,4) = 4 waves/EU = 16 waves/CU = 4 blocks,
// so barrier drains overlap across independent blocks (m114 wave-overlap).
// ---------------------------------------------------------------------------
template<int EPI>
__global__ __launch_bounds__(256, 4)
void gemm_split(const u16* __restrict__ Ah, const u16* __restrict__ Al,
                const u16* __restrict__ Bh, const u16* __restrict__ Bl,
                const float* __restrict__ bias, float bscale,
                float* __restrict__ outF, u16* __restrict__ outH,
                u16* __restrict__ outL)
{
    __shared__ u16 AsH[128][32];
    __shared__ u16 AsL[128][32];
    __shared__ u16 BsH[64][32];
    __shared__ u16 BsL[64][32];

    const int tid  = threadIdx.x;
    const int m0   = blockIdx.x * 128;
    const int n0   = blockIdx.y * 64;
    const int wid  = tid >> 6;
    const int lane = tid & 63;
    const int wr   = wid >> 1;
    const int wc   = wid & 1;
    const int fr   = lane & 15;
    const int fg   = lane >> 4;
    const int K    = DIM;

    f32x4 acc[4][2];
#pragma unroll
    for (int i = 0; i < 4; ++i)
#pragma unroll
        for (int j = 0; j < 2; ++j) { f32x4 z = {0.f, 0.f, 0.f, 0.f}; acc[i][j] = z; }

    const int gr = (wid << 4) + (lane >> 2);   // tile row this lane fetches
    const int gc = (lane & 3) * 8;             // elem col within K-chunk

    for (int kt = 0; kt < K; kt += 32) {
        __syncthreads();   // prev tile's LDS reads done
        GLD16(&Ah[(size_t)(m0 + gr) * K + kt + gc],      &AsH[(wid << 4)][0]);
        GLD16(&Ah[(size_t)(m0 + 64 + gr) * K + kt + gc], &AsH[64 + (wid << 4)][0]);
        GLD16(&Al[(size_t)(m0 + gr) * K + kt + gc],      &AsL[(wid << 4)][0]);
        GLD16(&Al[(size_t)(m0 + 64 + gr) * K + kt + gc], &AsL[64 + (wid << 4)][0]);
        GLD16(&Bh[(size_t)(n0 + gr) * K + kt + gc],      &BsH[(wid << 4)][0]);
        GLD16(&Bl[(size_t)(n0 + gr) * K + kt + gc],      &BsL[(wid << 4)][0]);
        __syncthreads();   // compiler drains vmcnt before barrier -> tile ready

        short8 afh[4], afl[4], bfh[2], bfl[2];
#pragma unroll
        for (int i = 0; i < 4; ++i) {
            afh[i] = *(const short8*)&AsH[wr * 64 + i * 16 + fr][fg * 8];
            afl[i] = *(const short8*)&AsL[wr * 64 + i * 16 + fr][fg * 8];
        }
#pragma unroll
        for (int j = 0; j < 2; ++j) {
            bfh[j] = *(const short8*)&BsH[wc * 32 + j * 16 + fr][fg * 8];
            bfl[j] = *(const short8*)&BsL[wc * 32 + j * 16 + fr][fg * 8];
        }
#pragma unroll
        for (int i = 0; i < 4; ++i)
#pragma unroll
            for (int j = 0; j < 2; ++j) {
                acc[i][j] = __builtin_amdgcn_mfma_f32_16x16x32_bf16(afl[i], bfh[j], acc[i][j], 0, 0, 0);
                acc[i][j] = __builtin_amdgcn_mfma_f32_16x16x32_bf16(afh[i], bfl[j], acc[i][j], 0, 0, 0);
                acc[i][j] = __builtin_amdgcn_mfma_f32_16x16x32_bf16(afh[i], bfh[j], acc[i][j], 0, 0, 0);
            }
    }

#pragma unroll
    for (int i = 0; i < 4; ++i)
#pragma unroll
        for (int j = 0; j < 2; ++j) {
            const int col = n0 + wc * 32 + j * 16 + fr;
            const float bv = bias[col] * bscale;
            if (EPI == 2) {
                const int row = m0 + wr * 64 + i * 16 + fg * 4;
                const int b  = row >> 11;
                const int s  = row & (SEQ - 1);
                const int hh = col >> 6;
                const int hd = col & (HD - 1);
                ushort4 pk;
                pk.x = bf16_rn(acc[i][j][0] + bv);
                pk.y = bf16_rn(acc[i][j][1] + bv);
                pk.z = bf16_rn(acc[i][j][2] + bv);
                pk.w = bf16_rn(acc[i][j][3] + bv);
                *(ushort4*)&outH[((size_t)(b * NUMH + hh) * HD + hd) * SEQ + s] = pk;
            } else {
#pragma unroll
                for (int r = 0; r < 4; ++r) {
                    const int row = m0 + wr * 64 + i * 16 + fg * 4 + r;
                    const float v = acc[i][j][r] + bv;
                    if (EPI == 0) {
                        outF[(size_t)row * DIM + col] = v;
                    } else {
                        const int b  = row >> 11;
                        const int s  = row & (SEQ - 1);
                        const int hh = col >> 6;
                        const int hd = col & (HD - 1);
                        const size_t idx = ((size_t)(b * NUMH + hh) * SEQ + s) * HD + hd;
                        const u16 hv = bf16_rn(v);
                        outH[idx] = hv;
                        outL[idx] = bf16_rn(v - bf16f(hv));
                    }
                }
            }
        }
}

// ---------------------------------------------------------------------------
// MFMA flash attention v4: PAIRED q-tiles {p, 31-p} + 8 warps (512 thr).
// Warps 0-3 own tile A (qA=p), warps 4-7 own tile B (qB=31-p); K/V staged
// once per block, shared by 8 waves. launch_bounds(512,4) = 2 blocks/CU =
// 16 waves/CU. XCD chunking, swizzled LDS, reg-prefetch, bpermute
// P-redistribute. Q pre-scaled by 0.125.
// ---------------------------------------------------------------------------
__global__ __launch_bounds__(512, 4)
void attn_mfma4(const u16* __restrict__ Qh, const u16* __restrict__ Ql,
                const u16* __restrict__ Kh, const u16* __restrict__ Kl,
                const u16* __restrict__ Vt,
                u16* __restrict__ ctxH, u16* __restrict__ ctxL)
{
    __shared__ u16 KsH[64 * 64];
    __shared__ u16 KsL[64 * 64];
    __shared__ u16 Vs [64 * 64];

    const int tid  = threadIdx.x;
    const int w    = tid >> 6;               // 0..7
    const int lane = tid & 63;
    const int lc   = lane & 15;
    const int g    = lane >> 4;

    // bijective XCD chunking: XCD x gets bh in [x*4, x*4+4); p ascending
    // (p=0 pairs {0,31} = heaviest) within each bh.
    const int orig = blockIdx.x;             // 512 blocks
    const int swz  = (orig & 7) * 64 + (orig >> 3);
    const int bh   = swz >> 4;
    const int p    = swz & 15;
    const int qA   = p, qB = 31 - p;
    const int qt_w = (w < 4) ? qA : qB;      // this warp's q-tile
    const int wq   = w & 3;                  // warp's 16-row slice in tile
    const int NT   = 32 - p;                 // staged tiles: kt = 0..qB

    const int bb = bh >> 4, hq = bh & 15;
    const size_t kqBase = (size_t)bh * SEQ * HD;
    const size_t vBase  = (size_t)bh * HD * SEQ;

    // Q B-frags: lane holds Q[q = qt_w*64 + wq*16 + lc][d = s2*32 + g*8 + j]
    short8 qh[2], ql[2];
    {
        const size_t ra = kqBase + (size_t)(qt_w * 64 + wq * 16 + lc) * HD;
        qh[0] = *(const short8*)&Qh[ra + g * 8];  qh[1] = *(const short8*)&Qh[ra + 32 + g * 8];
        ql[0] = *(const short8*)&Ql[ra + g * 8];  ql[1] = *(const short8*)&Ql[ra + 32 + g * 8];
    }

    f32x4 o[4];
#pragma unroll
    for (int f4 = 0; f4 < 4; ++f4) { f32x4 z = {0.f, 0.f, 0.f, 0.f}; o[f4] = z; }
    float mrun = -1e30f, lrun = 0.f;

    // staging: 512 threads, one 16B chunk per buffer each.
    // row = tid>>3 (0..63), col-slot = tid&7; swizzle ^((row&7)<<3)
    const int srow = tid >> 3;
    const int scol = (tid & 7) * 8;
    const int so   = srow * 64 + (scol ^ ((srow & 7) << 3));
    const int rsw  = (lc & 7) << 3;          // read-side swizzle

    short8 pf0, pf1, pf2;
    auto LOADT = [&](int kt) {
        const size_t kg = kqBase + (size_t)(kt * 64 + srow) * HD + scol;
        pf0 = *(const short8*)&Kh[kg];
        pf1 = *(const short8*)&Kl[kg];
        const size_t vg = vBase + (size_t)srow * SEQ + kt * 64 + scol;
        pf2 = *(const short8*)&Vt[vg];
    };
    LOADT(0);

    // bpermute constants for P redistribution
    const int a0 = (((g & 1) * 2 + 0) * 16 + lc) * 4;
    const int a1 = (((g & 1) * 2 + 1) * 16 + lc) * 4;
    const bool hi = ((g >> 1) & 1) != 0;

    for (int kt = 0; kt < NT; ++kt) {
        __syncthreads();                     // prev tile's LDS reads done
        *(short8*)&KsH[so] = pf0;
        *(short8*)&KsL[so] = pf1;
        *(short8*)&Vs [so] = pf2;
        __syncthreads();                     // tile ready
        if (kt + 1 < NT) LOADT(kt + 1);      // prefetch hides under compute

        if (kt <= qt_w) {                    // warp-uniform duty check
            const int k0 = kt * 64;

            // ---- scores: S^T[k][q] = mfma(K-frag, Q-frag) ----
            f32x4 sf[4];
#pragma unroll
            for (int f4 = 0; f4 < 4; ++f4) {
                f32x4 a = {0.f, 0.f, 0.f, 0.f};
#pragma unroll
                for (int s2 = 0; s2 < 2; ++s2) {
                    const int off = (f4 * 16 + lc) * 64 + ((s2 * 32 + g * 8) ^ rsw);
                    const short8 kh = *(const short8*)&KsH[off];
                    const short8 kl = *(const short8*)&KsL[off];
                    a = __builtin_amdgcn_mfma_f32_16x16x32_bf16(kh, ql[s2], a, 0, 0, 0);
                    a = __builtin_amdgcn_mfma_f32_16x16x32_bf16(kl, qh[s2], a, 0, 0, 0);
                    a = __builtin_amdgcn_mfma_f32_16x16x32_bf16(kh, qh[s2], a, 0, 0, 0);
                }
                sf[f4] = a;
            }

            // ---- mask + row-max + online-softmax (per-lane scalar state) ----
            const bool diag = (kt == qt_w);
            const int  qg   = qt_w * 64 + wq * 16 + lc;
            float pm = -1e30f;
#pragma unroll
            for (int f4 = 0; f4 < 4; ++f4)
#pragma unroll
                for (int r = 0; r < 4; ++r) {
                    float sv = sf[f4][r];
                    if (diag && (k0 + f4 * 16 + g * 4 + r > qg)) sv = -1e30f;
                    sf[f4][r] = sv;
                    pm = fmaxf(pm, sv);
                }
            pm = fmaxf(pm, __shfl_xor(pm, 16));
            pm = fmaxf(pm, __shfl_xor(pm, 32));
            const float mn = fmaxf(mrun, pm);
            const float sc = __expf(mrun - mn);
            mrun = mn; lrun *= sc;
#pragma unroll
            for (int f4 = 0; f4 < 4; ++f4) o[f4] *= sc;

            float ps = 0.f;
            u32 pk[4][2];
#pragma unroll
            for (int f4 = 0; f4 < 4; ++f4)
#pragma unroll
                for (int pr = 0; pr < 2; ++pr) {
                    const float p0 = __expf(sf[f4][pr * 2 + 0] - mn);
                    const float p1 = __expf(sf[f4][pr * 2 + 1] - mn);
                    ps += p0 + p1;
                    pk[f4][pr] = (u32)bf16_rn(p0) | ((u32)bf16_rn(p1) << 16);
                }
            ps += __shfl_xor(ps, 16);
            ps += __shfl_xor(ps, 32);
            lrun += ps;

            // ---- in-register P redistribute to PV B-frag layout ----
            u32 pb[2][4];
#pragma unroll
            for (int s2 = 0; s2 < 2; ++s2)
#pragma unroll
                for (int mm = 0; mm < 4; ++mm) {
                    const int addr = (mm < 2) ? a0 : a1;
                    const u32 t0 = (u32)__builtin_amdgcn_ds_bpermute(addr, (int)pk[s2 * 2 + 0][mm & 1]);
                    const u32 t1 = (u32)__builtin_amdgcn_ds_bpermute(addr, (int)pk[s2 * 2 + 1][mm & 1]);
                    pb[s2][mm] = hi ? t1 : t0;
                }

            // ---- PV: o^T[d][q] += mfma(V^T-frag, P^T-frag) ----
#pragma unroll
            for (int s2 = 0; s2 < 2; ++s2) {
                union { u32 u[4]; short8 s; } ua;
#pragma unroll
                for (int mm = 0; mm < 4; ++mm) ua.u[mm] = pb[s2][mm];
#pragma unroll
                for (int f4 = 0; f4 < 4; ++f4) {
                    const int off = (f4 * 16 + lc) * 64 + ((s2 * 32 + g * 8) ^ rsw);
                    const short8 vv = *(const short8*)&Vs[off];
                    o[f4] = __builtin_amdgcn_mfma_f32_16x16x32_bf16(vv, ua.s, o[f4], 0, 0, 0);
                }
            }
        }
    }

    // ---- epilogue: o^T[d][q]/l -> ctx bf16 h/l [M][DIM] ----
    const float iv = 1.f / lrun;
    const size_t rowA = (size_t)bb * SEQ + qt_w * 64 + wq * 16 + lc;
#pragma unroll
    for (int f4 = 0; f4 < 4; ++f4) {
        const int colb = hq * HD + f4 * 16 + g * 4;
        ushort4 h4, l4;
#pragma unroll
        for (int r = 0; r < 4; ++r) {
            const float v = o[f4][r] * iv;
            const u16 hv = bf16_rn(v);
            ((u16*)&h4)[r] = hv;
            ((u16*)&l4)[r] = bf16_rn(v - bf16f(hv));
        }
        *(ushort4*)&ctxH[rowA * DIM + colb] = h4;
        *(ushort4*)&ctxL[rowA * DIM + colb] = l4;
    }
}

// ---------------------------------------------------------------------------
extern "C" void kernel_launch(void* const* d_in, const int* in_sizes, int n_in,
                              void* d_out, int out_size, void* d_ws, size_t ws_size,
                              hipStream_t stream)
{
    const float* x  = (const float*)d_in[0];
    const float* Wq = (const float*)d_in[1];
    const float* bq = (const float*)d_in[2];
    const float* Wk = (const float*)d_in[3];
    const float* bk = (const float*)d_in[4];
    const float* Wv = (const float*)d_in[5];
    const float* bv = (const float*)d_in[6];
    const float* Wo = (const float*)d_in[7];
    const float* bo = (const float*)d_in[8];

    char* base = (char*)d_ws;
    const size_t MB = 1024 * 1024;
    u16* Qh_ = (u16*)(base + 0 * MB);
    u16* Ql_ = (u16*)(base + 8 * MB);
    u16* Kh_ = (u16*)(base + 16 * MB);
    u16* Kl_ = (u16*)(base + 24 * MB);
    u16* Vt_ = (u16*)(base + 32 * MB);
    u16* xh  = (u16*)(base + 40 * MB);   // reused as ctxH
    u16* xl  = (u16*)(base + 48 * MB);   // reused as ctxL
    u16* Wth = (u16*)(base + 56 * MB);
    u16* Wtl = (u16*)(base + 58 * MB);

    dim3 blk(256);
    dim3 gg(MROWS / 128, DIM / 64);
    dim3 gt(DIM / 32, DIM / 32);

    hipLaunchKernelGGL(convert_split, dim3(2048), blk, 0, stream,
                       x, xh, xl, MROWS * DIM / 4);

    // Q projection carries the 1/sqrt(Hd)=0.125 scale (exact in bf16 split)
    hipLaunchKernelGGL(transpose_split, gt, blk, 0, stream, Wq, Wth, Wtl, 0.125f);
    hipLaunchKernelGGL((gemm_split<1>), gg, blk, 0, stream,
                       xh, xl, Wth, Wtl, bq, 0.125f, nullptr, Qh_, Ql_);

    hipLaunchKernelGGL(transpose_split, gt, blk, 0, stream, Wk, Wth, Wtl, 1.0f);
    hipLaunchKernelGGL((gemm_split<1>), gg, blk, 0, stream,
                       xh, xl, Wth, Wtl, bk, 1.0f, nullptr, Kh_, Kl_);

    hipLaunchKernelGGL(transpose_split, gt, blk, 0, stream, Wv, Wth, Wtl, 1.0f);
    hipLaunchKernelGGL((gemm_split<2>), gg, blk, 0, stream,
                       xh, xl, Wth, Wtl, bv, 1.0f, nullptr, Vt_, nullptr);

    hipLaunchKernelGGL(attn_mfma4, dim3(NB * NUMH * 16), dim3(512), 0, stream,
                       Qh_, Ql_, Kh_, Kl_, Vt_, xh, xl);   // ctx -> xh/xl

    hipLaunchKernelGGL(transpose_split, gt, blk, 0, stream, Wo, Wth, Wtl, 1.0f);
    hipLaunchKernelGGL((gemm_split<0>), gg, blk, 0, stream,
                       xh, xl, Wth, Wtl, bo, 1.0f, (float*)d_out, nullptr, nullptr);
}